// Round 2
// baseline (504.016 us; speedup 1.0000x reference)
//
#include <hip/hip_runtime.h>
#include <hip/hip_bf16.h>
#include <math.h>

// AttentionWithBias: B=4, N=1024, d=1024, H=16, hd=64
// bf16 MFMA (16x16x32), fp32 accumulate, fp32 softmax+bias.

typedef __bf16 bf16;
typedef bf16 bf16x8 __attribute__((ext_vector_type(8)));
typedef bf16 bf16x4 __attribute__((ext_vector_type(4)));
typedef float floatx4 __attribute__((ext_vector_type(4)));

#define MFMA16(a, b, c) __builtin_amdgcn_mfma_f32_16x16x32_bf16((a), (b), (c), 0, 0, 0)

__device__ __forceinline__ void gload_lds16(const bf16* g, bf16* l) {
  // async global->LDS, 16B per lane; LDS dest = wave-uniform base + lane*16
  __builtin_amdgcn_global_load_lds(
      (const __attribute__((address_space(1))) unsigned int*)g,
      (__attribute__((address_space(3))) unsigned int*)l, 16, 0, 0);
}

// ---------------------------------------------------------------- convert
// dst layout (contiguous bf16): [x 4194304][Wq 1048576][Wk][Wv][Wo]
__global__ __launch_bounds__(256) void cvt_kernel(
    const float* __restrict__ x, const float* __restrict__ wq,
    const float* __restrict__ wk, const float* __restrict__ wv,
    const float* __restrict__ wo, bf16* __restrict__ dst) {
  long e = ((long)blockIdx.x * 256 + threadIdx.x) * 4;
  const float* src;
  if (e < 4194304) {
    src = x + e;
  } else {
    long r = (e - 4194304) >> 20;
    long off = (e - 4194304) & 1048575;
    src = (r == 0 ? wq : r == 1 ? wk : r == 2 ? wv : wo) + off;
  }
  float4 v = *reinterpret_cast<const float4*>(src);
  bf16x4 o = { (bf16)v.x, (bf16)v.y, (bf16)v.z, (bf16)v.w };
  *reinterpret_cast<bf16x4*>(dst + e) = o;
}

// ---------------------------------------------------------------- GEMM core
// C[128x128] = A[128x1024] . B[128x1024]^T  (both k-contiguous), m97 structure
__device__ __forceinline__ void gemm_mainloop(const bf16* __restrict__ Ag,
                                              const bf16* __restrict__ Bg,
                                              bf16* As, bf16* Bs,
                                              floatx4 acc[4][4]) {
  int tid = threadIdx.x;
  int w = tid >> 6, l = tid & 63, g = l >> 4, ln = l & 15;
  int wr = (w >> 1) << 6, wc = (w & 1) << 6;
  int lrow = w * 16 + (l >> 2);
  int lkc = (l & 3) * 8;
  for (int k0 = 0; k0 < 1024; k0 += 32) {
    __syncthreads();
    gload_lds16(Ag + (size_t)lrow * 1024 + k0 + lkc, As + w * 512);
    gload_lds16(Ag + (size_t)(lrow + 64) * 1024 + k0 + lkc, As + 2048 + w * 512);
    gload_lds16(Bg + (size_t)lrow * 1024 + k0 + lkc, Bs + w * 512);
    gload_lds16(Bg + (size_t)(lrow + 64) * 1024 + k0 + lkc, Bs + 2048 + w * 512);
    asm volatile("s_waitcnt vmcnt(0)" ::: "memory");
    __syncthreads();
    bf16x8 af[4], bfv[4];
#pragma unroll
    for (int t = 0; t < 4; t++) {
      af[t] = *(const bf16x8*)&As[(wr + t * 16 + ln) * 32 + g * 8];
      bfv[t] = *(const bf16x8*)&Bs[(wc + t * 16 + ln) * 32 + g * 8];
    }
#pragma unroll
    for (int i = 0; i < 4; i++)
#pragma unroll
      for (int j = 0; j < 4; j++)
        acc[i][j] = MFMA16(af[i], bfv[j], acc[i][j]);
  }
}

// ---------------------------------------------------------------- QKV projection
__global__ __launch_bounds__(256) void qkv_proj(
    const bf16* __restrict__ xb, const bf16* __restrict__ wqkv,
    bf16* __restrict__ Qo, bf16* __restrict__ Ko, bf16* __restrict__ Vo) {
  __shared__ bf16 As[4096], Bs[4096];
  const floatx4 z4 = {0.f, 0.f, 0.f, 0.f};
  floatx4 acc[4][4];
#pragma unroll
  for (int i = 0; i < 4; i++)
#pragma unroll
    for (int j = 0; j < 4; j++) acc[i][j] = z4;
  int z = blockIdx.z;
  const bf16* Ag = xb + (size_t)blockIdx.x * 128 * 1024;
  const bf16* Bg = wqkv + (size_t)z * 1048576 + (size_t)blockIdx.y * 128 * 1024;
  gemm_mainloop(Ag, Bg, As, Bs, acc);
  bf16* dst = z == 0 ? Qo : (z == 1 ? Ko : Vo);
  int tid = threadIdx.x, w = tid >> 6, l = tid & 63, g = l >> 4, ln = l & 15;
  int mbase = blockIdx.x * 128 + ((w >> 1) << 6);
  int ibase = blockIdx.y * 128 + ((w & 1) << 6);
#pragma unroll
  for (int i = 0; i < 4; i++)
#pragma unroll
    for (int j = 0; j < 4; j++)
#pragma unroll
      for (int r = 0; r < 4; r++) {
        int m = mbase + i * 16 + g * 4 + r;       // C/D layout: row=(l>>4)*4+reg
        int col = ibase + j * 16 + ln;            //            col=lane&15
        int b = m >> 10, n = m & 1023, h = col >> 6, di = col & 63;
        dst[((size_t)((b * 16 + h) * 1024 + n) << 6) + di] = (bf16)acc[i][j][r];
      }
}

// ---------------------------------------------------------------- flash attention
// grid: (16 q-tiles, 64 bh). Block 256 = 4 waves; wave handles 16 q-rows.
// Round-2: bias double-buffered in regs; V-transpose staging remapped so kc is
// wave-uniform (store addr lane-contiguous -> no 16-way bank conflict).
__global__ __launch_bounds__(256) void flash_kernel(
    const bf16* __restrict__ Q, const bf16* __restrict__ Kg,
    const bf16* __restrict__ Vg, const float* __restrict__ bias,
    bf16* __restrict__ Ao) {
  __shared__ bf16 Klds[64 * 72];      // [key][d]
  __shared__ bf16 Vtlds[64 * 72];     // [d][key]
  __shared__ bf16 Plds[4 * 16 * 72];  // per-wave P [qrow][key]
  int tid = threadIdx.x;
  int w = tid >> 6, l = tid & 63, g = l >> 4, ln = l & 15;
  int qt = blockIdx.x;   // 0..15
  int bh = blockIdx.y;   // 0..63
  size_t bhN = (size_t)bh * 1024;

  // Q fragments (A-layout: m=lane&15, k=(lane>>4)*8+j)
  const bf16* qptr = Q + (bhN + qt * 64 + w * 16 + ln) * 64;
  bf16x8 qf0 = *(const bf16x8*)(qptr + g * 8);
  bf16x8 qf1 = *(const bf16x8*)(qptr + 32 + g * 8);

  const floatx4 z4 = {0.f, 0.f, 0.f, 0.f};
  floatx4 o[4];
  float m_i[4], l_i[4];
#pragma unroll
  for (int i = 0; i < 4; i++) { o[i] = z4; m_i[i] = -1e30f; l_i[i] = 0.f; }

  // bias base: rows (w*16+g*4+r), cols (t*16+ln); double-buffered in regs
  const float* bbase = bias + ((bhN + qt * 64 + w * 16 + g * 4) << 10) + ln;
  float bc[4][4];
#pragma unroll
  for (int t = 0; t < 4; t++)
#pragma unroll
    for (int r = 0; r < 4; r++) bc[t][r] = bbase[(size_t)r * 1024 + t * 16];

  bf16* pw = Plds + w * 16 * 72;
  int skey = l;                 // staging: key = lane (contiguous LDS stores)
  int skc2 = w * 2;             // each wave covers kc = {2w, 2w+1}

  for (int kb = 0; kb < 16; kb++) {
    __syncthreads();
    const bf16* krow = Kg + (bhN + kb * 64 + skey) * 64;
    const bf16* vrow = Vg + (bhN + kb * 64 + skey) * 64;
#pragma unroll
    for (int c0 = 0; c0 < 2; c0++) {
      int kc = skc2 + c0;
      *(bf16x8*)&Klds[skey * 72 + kc * 8] = *(const bf16x8*)(krow + kc * 8);
      bf16x8 vv = *(const bf16x8*)(vrow + kc * 8);
#pragma unroll
      for (int j = 0; j < 8; j++) Vtlds[(kc * 8 + j) * 72 + skey] = vv[j];
    }
    __syncthreads();

    // prefetch next iteration's bias (no dependency -> overlaps everything)
    float bn[4][4];
    if (kb < 15) {
      const float* bp = bbase + (kb + 1) * 64;
#pragma unroll
      for (int t = 0; t < 4; t++)
#pragma unroll
        for (int r = 0; r < 4; r++) bn[t][r] = bp[(size_t)r * 1024 + t * 16];
    }

    // S = Q K^T
    floatx4 s[4];
#pragma unroll
    for (int t = 0; t < 4; t++) {
      s[t] = z4;
      bf16x8 kf0 = *(const bf16x8*)&Klds[(t * 16 + ln) * 72 + g * 8];
      bf16x8 kf1 = *(const bf16x8*)&Klds[(t * 16 + ln) * 72 + 32 + g * 8];
      s[t] = MFMA16(qf0, kf0, s[t]);
      s[t] = MFMA16(qf1, kf1, s[t]);
    }
    // scale + bias from registers (zero-latency)
#pragma unroll
    for (int t = 0; t < 4; t++)
#pragma unroll
      for (int r = 0; r < 4; r++)
        s[t][r] = fmaf(s[t][r], 0.125f, bc[t][r]);

    // online softmax
    float cmax[4], rs[4], alpha[4];
#pragma unroll
    for (int r = 0; r < 4; r++)
      cmax[r] = fmaxf(fmaxf(s[0][r], s[1][r]), fmaxf(s[2][r], s[3][r]));
#pragma unroll
    for (int mk = 1; mk < 16; mk <<= 1)
#pragma unroll
      for (int r = 0; r < 4; r++)
        cmax[r] = fmaxf(cmax[r], __shfl_xor(cmax[r], mk, 64));
#pragma unroll
    for (int r = 0; r < 4; r++) {
      float mn = fmaxf(m_i[r], cmax[r]);
      alpha[r] = __expf(m_i[r] - mn);
      m_i[r] = mn;
      rs[r] = 0.f;
    }
#pragma unroll
    for (int t = 0; t < 4; t++)
#pragma unroll
      for (int r = 0; r < 4; r++) {
        float p = __expf(s[t][r] - m_i[r]);
        s[t][r] = p;
        rs[r] += p;
      }
#pragma unroll
    for (int mk = 1; mk < 16; mk <<= 1)
#pragma unroll
      for (int r = 0; r < 4; r++) rs[r] += __shfl_xor(rs[r], mk, 64);
#pragma unroll
    for (int r = 0; r < 4; r++) l_i[r] = l_i[r] * alpha[r] + rs[r];
#pragma unroll
    for (int dt = 0; dt < 4; dt++)
#pragma unroll
      for (int r = 0; r < 4; r++) o[dt][r] *= alpha[r];

    // P: C-layout -> LDS -> A-layout frags (wave-private region)
#pragma unroll
    for (int t = 0; t < 4; t++)
#pragma unroll
      for (int r = 0; r < 4; r++)
        pw[(g * 4 + r) * 72 + t * 16 + ln] = (bf16)s[t][r];
    asm volatile("s_waitcnt lgkmcnt(0)" ::: "memory");

    bf16x8 pf0 = *(const bf16x8*)&pw[ln * 72 + g * 8];
    bf16x8 pf1 = *(const bf16x8*)&pw[ln * 72 + 32 + g * 8];
#pragma unroll
    for (int dt = 0; dt < 4; dt++) {
      bf16x8 vf0 = *(const bf16x8*)&Vtlds[(dt * 16 + ln) * 72 + g * 8];
      bf16x8 vf1 = *(const bf16x8*)&Vtlds[(dt * 16 + ln) * 72 + 32 + g * 8];
      o[dt] = MFMA16(pf0, vf0, o[dt]);
      o[dt] = MFMA16(pf1, vf1, o[dt]);
    }
#pragma unroll
    for (int t = 0; t < 4; t++)
#pragma unroll
      for (int r = 0; r < 4; r++) bc[t][r] = bn[t][r];
  }

  // epilogue: O /= l, write attn_out [B*N, 1024] bf16 at col h*64+d
  int b = bh >> 4, h = bh & 15;
#pragma unroll
  for (int r = 0; r < 4; r++) {
    float inv = 1.f / l_i[r];
    int row = b * 1024 + qt * 64 + w * 16 + g * 4 + r;
    bf16* op = Ao + (size_t)row * 1024 + h * 64 + ln;
#pragma unroll
    for (int dt = 0; dt < 4; dt++) op[dt * 16] = (bf16)(o[dt][r] * inv);
  }
}

// ---------------------------------------------------------------- output projection
// Round-2: 128x64 tiles -> 512 blocks = 2 blocks/CU (was 1/CU -> staging exposed)
__global__ __launch_bounds__(256) void out_proj(const bf16* __restrict__ Ab,
                                                const bf16* __restrict__ wob,
                                                float* __restrict__ C) {
  __shared__ bf16 As[4096], Bs[2048];
  const floatx4 z4 = {0.f, 0.f, 0.f, 0.f};
  floatx4 acc[4][2];
#pragma unroll
  for (int i = 0; i < 4; i++)
#pragma unroll
    for (int j = 0; j < 2; j++) acc[i][j] = z4;
  const bf16* Ag = Ab + (size_t)blockIdx.x * 128 * 1024;
  const bf16* Bg = wob + (size_t)blockIdx.y * 64 * 1024;
  int tid = threadIdx.x;
  int w = tid >> 6, l = tid & 63, g = l >> 4, ln = l & 15;
  int wr = (w >> 1) << 6, wc = (w & 1) << 5;
  int lrow = w * 16 + (l >> 2);
  int lkc = (l & 3) * 8;
  for (int k0 = 0; k0 < 1024; k0 += 32) {
    __syncthreads();
    gload_lds16(Ag + (size_t)lrow * 1024 + k0 + lkc, As + w * 512);
    gload_lds16(Ag + (size_t)(lrow + 64) * 1024 + k0 + lkc, As + 2048 + w * 512);
    gload_lds16(Bg + (size_t)lrow * 1024 + k0 + lkc, Bs + w * 512);
    asm volatile("s_waitcnt vmcnt(0)" ::: "memory");
    __syncthreads();
    bf16x8 af[4], bfv[2];
#pragma unroll
    for (int t = 0; t < 4; t++)
      af[t] = *(const bf16x8*)&As[(wr + t * 16 + ln) * 32 + g * 8];
#pragma unroll
    for (int t = 0; t < 2; t++)
      bfv[t] = *(const bf16x8*)&Bs[(wc + t * 16 + ln) * 32 + g * 8];
#pragma unroll
    for (int i = 0; i < 4; i++)
#pragma unroll
      for (int j = 0; j < 2; j++)
        acc[i][j] = MFMA16(af[i], bfv[j], acc[i][j]);
  }
  int mbase = blockIdx.x * 128 + wr;
  int cbase = blockIdx.y * 64 + wc;
#pragma unroll
  for (int i = 0; i < 4; i++)
#pragma unroll
    for (int j = 0; j < 2; j++)
#pragma unroll
      for (int r = 0; r < 4; r++)
        C[(size_t)(mbase + i * 16 + g * 4 + r) * 1024 + cbase + j * 16 + ln] =
            acc[i][j][r];
}

// ---------------------------------------------------------------- launch
extern "C" void kernel_launch(void* const* d_in, const int* in_sizes, int n_in,
                              void* d_out, int out_size, void* d_ws, size_t ws_size,
                              hipStream_t stream) {
  const float* x = (const float*)d_in[0];
  const float* bias = (const float*)d_in[1];
  const float* Wq = (const float*)d_in[2];
  const float* Wk = (const float*)d_in[3];
  const float* Wv = (const float*)d_in[4];
  const float* Wo = (const float*)d_in[5];
  float* out = (float*)d_out;

  bf16* xb = (bf16*)d_ws;            // 4194304
  bf16* wqkv = xb + 4194304;         // 3*1048576 (Wq,Wk,Wv)
  bf16* wob = wqkv + 3 * 1048576;    // 1048576
  bf16* Qb = wob + 1048576;          // 4194304  [B,H,N,64]
  bf16* Kb = Qb + 4194304;           // 4194304
  bf16* Vb = Kb + 4194304;           // 4194304
  bf16* Ao = Vb + 4194304;           // 4194304  [B*N, 1024]

  cvt_kernel<<<8192, 256, 0, stream>>>(x, Wq, Wk, Wv, Wo, xb);
  qkv_proj<<<dim3(32, 8, 3), 256, 0, stream>>>(xb, wqkv, Qb, Kb, Vb);
  flash_kernel<<<dim3(16, 64), 256, 0, stream>>>(Qb, Kb, Vb, bias, Ao);
  out_proj<<<dim3(32, 16), 256, 0, stream>>>(Ao, wob, out);
}

// Round 3
// 461.032 us; speedup vs baseline: 1.0932x; 1.0932x over previous
//
#include <hip/hip_runtime.h>
#include <hip/hip_bf16.h>
#include <math.h>

// AttentionWithBias: B=4, N=1024, d=1024, H=16, hd=64
// bf16 MFMA (16x16x32), fp32 accumulate, fp32 softmax+bias.

typedef __bf16 bf16;
typedef bf16 bf16x8 __attribute__((ext_vector_type(8)));
typedef bf16 bf16x4 __attribute__((ext_vector_type(4)));
typedef float floatx4 __attribute__((ext_vector_type(4)));

#define MFMA16(a, b, c) __builtin_amdgcn_mfma_f32_16x16x32_bf16((a), (b), (c), 0, 0, 0)

__device__ __forceinline__ void gload_lds16(const bf16* g, bf16* l) {
  __builtin_amdgcn_global_load_lds(
      (const __attribute__((address_space(1))) unsigned int*)g,
      (__attribute__((address_space(3))) unsigned int*)l, 16, 0, 0);
}

// ---------------------------------------------------------------- convert
__global__ __launch_bounds__(256) void cvt_kernel(
    const float* __restrict__ x, const float* __restrict__ wq,
    const float* __restrict__ wk, const float* __restrict__ wv,
    const float* __restrict__ wo, bf16* __restrict__ dst) {
  long e = ((long)blockIdx.x * 256 + threadIdx.x) * 4;
  const float* src;
  if (e < 4194304) {
    src = x + e;
  } else {
    long r = (e - 4194304) >> 20;
    long off = (e - 4194304) & 1048575;
    src = (r == 0 ? wq : r == 1 ? wk : r == 2 ? wv : wo) + off;
  }
  float4 v = *reinterpret_cast<const float4*>(src);
  bf16x4 o = { (bf16)v.x, (bf16)v.y, (bf16)v.z, (bf16)v.w };
  *reinterpret_cast<bf16x4*>(dst + e) = o;
}

// ---------------------------------------------------------------- GEMM core
__device__ __forceinline__ void gemm_mainloop(const bf16* __restrict__ Ag,
                                              const bf16* __restrict__ Bg,
                                              bf16* As, bf16* Bs,
                                              floatx4 acc[4][4]) {
  int tid = threadIdx.x;
  int w = tid >> 6, l = tid & 63, g = l >> 4, ln = l & 15;
  int wr = (w >> 1) << 6, wc = (w & 1) << 6;
  int lrow = w * 16 + (l >> 2);
  int lkc = (l & 3) * 8;
  for (int k0 = 0; k0 < 1024; k0 += 32) {
    __syncthreads();
    gload_lds16(Ag + (size_t)lrow * 1024 + k0 + lkc, As + w * 512);
    gload_lds16(Ag + (size_t)(lrow + 64) * 1024 + k0 + lkc, As + 2048 + w * 512);
    gload_lds16(Bg + (size_t)lrow * 1024 + k0 + lkc, Bs + w * 512);
    gload_lds16(Bg + (size_t)(lrow + 64) * 1024 + k0 + lkc, Bs + 2048 + w * 512);
    asm volatile("s_waitcnt vmcnt(0)" ::: "memory");
    __syncthreads();
    bf16x8 af[4], bfv[4];
#pragma unroll
    for (int t = 0; t < 4; t++) {
      af[t] = *(const bf16x8*)&As[(wr + t * 16 + ln) * 32 + g * 8];
      bfv[t] = *(const bf16x8*)&Bs[(wc + t * 16 + ln) * 32 + g * 8];
    }
#pragma unroll
    for (int i = 0; i < 4; i++)
#pragma unroll
      for (int j = 0; j < 4; j++)
        acc[i][j] = MFMA16(af[i], bfv[j], acc[i][j]);
  }
}

// ---------------------------------------------------------------- QKV projection
__global__ __launch_bounds__(256) void qkv_proj(
    const bf16* __restrict__ xb, const bf16* __restrict__ wqkv,
    bf16* __restrict__ Qo, bf16* __restrict__ Ko, bf16* __restrict__ Vo) {
  __shared__ bf16 As[4096], Bs[4096];
  const floatx4 z4 = {0.f, 0.f, 0.f, 0.f};
  floatx4 acc[4][4];
#pragma unroll
  for (int i = 0; i < 4; i++)
#pragma unroll
    for (int j = 0; j < 4; j++) acc[i][j] = z4;
  int z = blockIdx.z;
  const bf16* Ag = xb + (size_t)blockIdx.x * 128 * 1024;
  const bf16* Bg = wqkv + (size_t)z * 1048576 + (size_t)blockIdx.y * 128 * 1024;
  gemm_mainloop(Ag, Bg, As, Bs, acc);
  bf16* dst = z == 0 ? Qo : (z == 1 ? Ko : Vo);
  int tid = threadIdx.x, w = tid >> 6, l = tid & 63, g = l >> 4, ln = l & 15;
  int mbase = blockIdx.x * 128 + ((w >> 1) << 6);
  int ibase = blockIdx.y * 128 + ((w & 1) << 6);
#pragma unroll
  for (int i = 0; i < 4; i++)
#pragma unroll
    for (int j = 0; j < 4; j++)
#pragma unroll
      for (int r = 0; r < 4; r++) {
        int m = mbase + i * 16 + g * 4 + r;
        int col = ibase + j * 16 + ln;
        int b = m >> 10, n = m & 1023, h = col >> 6, di = col & 63;
        dst[((size_t)((b * 16 + h) * 1024 + n) << 6) + di] = (bf16)acc[i][j][r];
      }
}

// ---------------------------------------------------------------- flash attention
// Round-3: software-pipelined. K/V for kb+1 prefetched to VGPRs at top of
// iter kb; LDS double-buffered; single __syncthreads per iteration.
__global__ __launch_bounds__(256) void flash_kernel(
    const bf16* __restrict__ Q, const bf16* __restrict__ Kg,
    const bf16* __restrict__ Vg, const float* __restrict__ bias,
    bf16* __restrict__ Ao) {
  __shared__ bf16 Klds[2][64 * 72];   // [buf][key][d]
  __shared__ bf16 Vtlds[2][64 * 72];  // [buf][d][key]
  __shared__ bf16 Plds[4 * 16 * 72];  // per-wave P [qrow][key]
  int tid = threadIdx.x;
  int w = tid >> 6, l = tid & 63, g = l >> 4, ln = l & 15;
  int qt = blockIdx.x;   // 0..15
  int bh = blockIdx.y;   // 0..63
  size_t bhN = (size_t)bh * 1024;

  // staging mapping: skey = lane (contiguous LDS), wave covers kc={2w,2w+1}
  int skey = l, skc2 = w * 2;
  const bf16* Kbase = Kg + (bhN + skey) * 64;
  const bf16* Vbase = Vg + (bhN + skey) * 64;

  bf16x8 kr[2], vr[2];
#pragma unroll
  for (int c = 0; c < 2; c++) {   // prefetch kb=0
    kr[c] = *(const bf16x8*)(Kbase + (skc2 + c) * 8);
    vr[c] = *(const bf16x8*)(Vbase + (skc2 + c) * 8);
  }

  // Q fragments (A-layout: m=lane&15, k=(lane>>4)*8+j)
  const bf16* qptr = Q + (bhN + qt * 64 + w * 16 + ln) * 64;
  bf16x8 qf0 = *(const bf16x8*)(qptr + g * 8);
  bf16x8 qf1 = *(const bf16x8*)(qptr + 32 + g * 8);

  // bias double-buffered in regs; rows (w*16+g*4+r), cols (t*16+ln)
  const float* bbase = bias + ((bhN + qt * 64 + w * 16 + g * 4) << 10) + ln;
  float bc[4][4];
#pragma unroll
  for (int t = 0; t < 4; t++)
#pragma unroll
    for (int r = 0; r < 4; r++) bc[t][r] = bbase[(size_t)r * 1024 + t * 16];

  const floatx4 z4 = {0.f, 0.f, 0.f, 0.f};
  floatx4 o[4];
  float m_i[4], l_i[4];
#pragma unroll
  for (int i = 0; i < 4; i++) { o[i] = z4; m_i[i] = -1e30f; l_i[i] = 0.f; }

  // write kb=0 into buf 0
#pragma unroll
  for (int c = 0; c < 2; c++) {
    int kc = skc2 + c;
    *(bf16x8*)&Klds[0][skey * 72 + kc * 8] = kr[c];
#pragma unroll
    for (int j = 0; j < 8; j++) Vtlds[0][(kc * 8 + j) * 72 + skey] = vr[c][j];
  }
  __syncthreads();

  bf16* pw = Plds + w * 16 * 72;

#pragma unroll 2
  for (int kb = 0; kb < 16; kb++) {
    int cur = kb & 1, nxt = cur ^ 1;
    // ---- prefetch kb+1 (global -> VGPR), full iteration of latency cover
    float bn[4][4];
    if (kb < 15) {
#pragma unroll
      for (int c = 0; c < 2; c++) {
        kr[c] = *(const bf16x8*)(Kbase + (kb + 1) * 4096 + (skc2 + c) * 8);
        vr[c] = *(const bf16x8*)(Vbase + (kb + 1) * 4096 + (skc2 + c) * 8);
      }
      const float* bp = bbase + (kb + 1) * 64;
#pragma unroll
      for (int t = 0; t < 4; t++)
#pragma unroll
        for (int r = 0; r < 4; r++) bn[t][r] = bp[(size_t)r * 1024 + t * 16];
    }

    // ---- S = Q K^T from buffer cur
    floatx4 s[4];
#pragma unroll
    for (int t = 0; t < 4; t++) {
      s[t] = z4;
      bf16x8 kf0 = *(const bf16x8*)&Klds[cur][(t * 16 + ln) * 72 + g * 8];
      bf16x8 kf1 = *(const bf16x8*)&Klds[cur][(t * 16 + ln) * 72 + 32 + g * 8];
      s[t] = MFMA16(qf0, kf0, s[t]);
      s[t] = MFMA16(qf1, kf1, s[t]);
    }
#pragma unroll
    for (int t = 0; t < 4; t++)
#pragma unroll
      for (int r = 0; r < 4; r++)
        s[t][r] = fmaf(s[t][r], 0.125f, bc[t][r]);

    // ---- online softmax (rows live across 16 lanes of group g)
    float cmax[4], rs[4], alpha[4];
#pragma unroll
    for (int r = 0; r < 4; r++)
      cmax[r] = fmaxf(fmaxf(s[0][r], s[1][r]), fmaxf(s[2][r], s[3][r]));
#pragma unroll
    for (int mk = 1; mk < 16; mk <<= 1)
#pragma unroll
      for (int r = 0; r < 4; r++)
        cmax[r] = fmaxf(cmax[r], __shfl_xor(cmax[r], mk, 64));
#pragma unroll
    for (int r = 0; r < 4; r++) {
      float mn = fmaxf(m_i[r], cmax[r]);
      alpha[r] = __expf(m_i[r] - mn);
      m_i[r] = mn;
      rs[r] = 0.f;
    }
#pragma unroll
    for (int t = 0; t < 4; t++)
#pragma unroll
      for (int r = 0; r < 4; r++) {
        float p = __expf(s[t][r] - m_i[r]);
        s[t][r] = p;
        rs[r] += p;
      }
#pragma unroll
    for (int mk = 1; mk < 16; mk <<= 1)
#pragma unroll
      for (int r = 0; r < 4; r++) rs[r] += __shfl_xor(rs[r], mk, 64);
#pragma unroll
    for (int r = 0; r < 4; r++) l_i[r] = l_i[r] * alpha[r] + rs[r];
#pragma unroll
    for (int dt = 0; dt < 4; dt++)
#pragma unroll
      for (int r = 0; r < 4; r++) o[dt][r] *= alpha[r];

    // ---- P: C-layout -> LDS -> A-layout frags (wave-private region)
#pragma unroll
    for (int t = 0; t < 4; t++)
#pragma unroll
      for (int r = 0; r < 4; r++)
        pw[(g * 4 + r) * 72 + t * 16 + ln] = (bf16)s[t][r];
    asm volatile("s_waitcnt lgkmcnt(0)" ::: "memory");

    bf16x8 pf0 = *(const bf16x8*)&pw[ln * 72 + g * 8];
    bf16x8 pf1 = *(const bf16x8*)&pw[ln * 72 + 32 + g * 8];
#pragma unroll
    for (int dt = 0; dt < 4; dt++) {
      bf16x8 vf0 = *(const bf16x8*)&Vtlds[cur][(dt * 16 + ln) * 72 + g * 8];
      bf16x8 vf1 = *(const bf16x8*)&Vtlds[cur][(dt * 16 + ln) * 72 + 32 + g * 8];
      o[dt] = MFMA16(pf0, vf0, o[dt]);
      o[dt] = MFMA16(pf1, vf1, o[dt]);
    }

    // ---- write prefetched kb+1 into buffer nxt, then one barrier
    if (kb < 15) {
#pragma unroll
      for (int c = 0; c < 2; c++) {
        int kc = skc2 + c;
        *(bf16x8*)&Klds[nxt][skey * 72 + kc * 8] = kr[c];
#pragma unroll
        for (int j = 0; j < 8; j++)
          Vtlds[nxt][(kc * 8 + j) * 72 + skey] = vr[c][j];
      }
#pragma unroll
      for (int t = 0; t < 4; t++)
#pragma unroll
        for (int r = 0; r < 4; r++) bc[t][r] = bn[t][r];
      __syncthreads();
    }
  }

  // epilogue: O /= l, write attn_out [B*N, 1024] bf16 at col h*64+d
  int b = bh >> 4, h = bh & 15;
#pragma unroll
  for (int r = 0; r < 4; r++) {
    float inv = 1.f / l_i[r];
    int row = b * 1024 + qt * 64 + w * 16 + g * 4 + r;
    bf16* op = Ao + (size_t)row * 1024 + h * 64 + ln;
#pragma unroll
    for (int dt = 0; dt < 4; dt++) op[dt * 16] = (bf16)(o[dt][r] * inv);
  }
}

// ---------------------------------------------------------------- output projection
__global__ __launch_bounds__(256) void out_proj(const bf16* __restrict__ Ab,
                                                const bf16* __restrict__ wob,
                                                float* __restrict__ C) {
  __shared__ bf16 As[4096], Bs[2048];
  const floatx4 z4 = {0.f, 0.f, 0.f, 0.f};
  floatx4 acc[4][2];
#pragma unroll
  for (int i = 0; i < 4; i++)
#pragma unroll
    for (int j = 0; j < 2; j++) acc[i][j] = z4;
  const bf16* Ag = Ab + (size_t)blockIdx.x * 128 * 1024;
  const bf16* Bg = wob + (size_t)blockIdx.y * 64 * 1024;
  int tid = threadIdx.x;
  int w = tid >> 6, l = tid & 63, g = l >> 4, ln = l & 15;
  int wr = (w >> 1) << 6, wc = (w & 1) << 5;
  int lrow = w * 16 + (l >> 2);
  int lkc = (l & 3) * 8;
  for (int k0 = 0; k0 < 1024; k0 += 32) {
    __syncthreads();
    gload_lds16(Ag + (size_t)lrow * 1024 + k0 + lkc, As + w * 512);
    gload_lds16(Ag + (size_t)(lrow + 64) * 1024 + k0 + lkc, As + 2048 + w * 512);
    gload_lds16(Bg + (size_t)lrow * 1024 + k0 + lkc, Bs + w * 512);
    asm volatile("s_waitcnt vmcnt(0)" ::: "memory");
    __syncthreads();
    bf16x8 af[4], bfv[2];
#pragma unroll
    for (int t = 0; t < 4; t++)
      af[t] = *(const bf16x8*)&As[(wr + t * 16 + ln) * 32 + g * 8];
#pragma unroll
    for (int t = 0; t < 2; t++)
      bfv[t] = *(const bf16x8*)&Bs[(wc + t * 16 + ln) * 32 + g * 8];
#pragma unroll
    for (int i = 0; i < 4; i++)
#pragma unroll
      for (int j = 0; j < 2; j++)
        acc[i][j] = MFMA16(af[i], bfv[j], acc[i][j]);
  }
  int mbase = blockIdx.x * 128 + wr;
  int cbase = blockIdx.y * 64 + wc;
#pragma unroll
  for (int i = 0; i < 4; i++)
#pragma unroll
    for (int j = 0; j < 2; j++)
#pragma unroll
      for (int r = 0; r < 4; r++)
        C[(size_t)(mbase + i * 16 + g * 4 + r) * 1024 + cbase + j * 16 + ln] =
            acc[i][j][r];
}

// ---------------------------------------------------------------- launch
extern "C" void kernel_launch(void* const* d_in, const int* in_sizes, int n_in,
                              void* d_out, int out_size, void* d_ws, size_t ws_size,
                              hipStream_t stream) {
  const float* x = (const float*)d_in[0];
  const float* bias = (const float*)d_in[1];
  const float* Wq = (const float*)d_in[2];
  const float* Wk = (const float*)d_in[3];
  const float* Wv = (const float*)d_in[4];
  const float* Wo = (const float*)d_in[5];
  float* out = (float*)d_out;

  bf16* xb = (bf16*)d_ws;            // 4194304
  bf16* wqkv = xb + 4194304;         // 3*1048576 (Wq,Wk,Wv)
  bf16* wob = wqkv + 3 * 1048576;    // 1048576
  bf16* Qb = wob + 1048576;          // 4194304  [B,H,N,64]
  bf16* Kb = Qb + 4194304;           // 4194304
  bf16* Vb = Kb + 4194304;           // 4194304
  bf16* Ao = Vb + 4194304;           // 4194304  [B*N, 1024]

  cvt_kernel<<<8192, 256, 0, stream>>>(x, Wq, Wk, Wv, Wo, xb);
  qkv_proj<<<dim3(32, 8, 3), 256, 0, stream>>>(xb, wqkv, Qb, Kb, Vb);
  flash_kernel<<<dim3(16, 64), 256, 0, stream>>>(Qb, Kb, Vb, bias, Ao);
  out_proj<<<dim3(32, 16), 256, 0, stream>>>(Ao, wob, out);
}